// Round 20
// baseline (108.493 us; speedup 1.0000x reference)
//
#include <hip/hip_runtime.h>
#include <math.h>

#define NN 8192

typedef _Float16 h4v __attribute__((ext_vector_type(4)));
typedef float f4v __attribute__((ext_vector_type(4)));

__device__ __forceinline__ float fexp2(float x) {
    float r;
    asm("v_exp_f32 %0, %1" : "=v"(r) : "v"(x));
    return r;
}

// ---------------- kernel 1: row normalize ----------------
__global__ __launch_bounds__(256) void k_norm(const float* __restrict__ in,
                                              float* __restrict__ xn) {
    int r = blockIdx.x * 256 + threadIdx.x;
    const float4* p = reinterpret_cast<const float4*>(in + (size_t)r * 8);
    float4 a = p[0], b = p[1];
    float ss = a.x*a.x + a.y*a.y + a.z*a.z + a.w*a.w
             + b.x*b.x + b.y*b.y + b.z*b.z + b.w*b.w;
    float inv = 1.0f / (sqrtf(ss) + 1e-12f);
    a.x *= inv; a.y *= inv; a.z *= inv; a.w *= inv;
    b.x *= inv; b.y *= inv; b.z *= inv; b.w *= inv;
    float4* o = reinterpret_cast<float4*>(xn + (size_t)r * 8);
    o[0] = a; o[1] = b;
}

// ---- kernel 2: adjacency row-sum; LDS-staged f32 (threshold exact); seg-fastest out (r18) ----
template<int SEGS>
__global__ __launch_bounds__(256) void k_adj_t(const float* __restrict__ xn,
                                               const float* __restrict__ in,
                                               float* __restrict__ pns) {
    constexpr int JC = NN / SEGS;
    constexpr int RSTR = NN / 2;
    __shared__ float4 sx[JC * 2];
    __shared__ float4 si[JC * 2];
    int tid = threadIdx.x;
    int r = blockIdx.x * 256 + tid;          // [0, NN/2)
    int seg = blockIdx.y;
    int j0 = seg * JC;

    for (int idx = tid; idx < JC * 2; idx += 256) {
        sx[idx] = reinterpret_cast<const float4*>(xn + (size_t)j0 * 8)[idx];
        si[idx] = reinterpret_cast<const float4*>(in + (size_t)j0 * 8)[idx];
    }
    float x[2][8];
    #pragma unroll
    for (int i = 0; i < 2; ++i) {
        const float4* xp = reinterpret_cast<const float4*>(xn + (size_t)(r + i * RSTR) * 8);
        float4 a = xp[0], b = xp[1];
        x[i][0]=a.x; x[i][1]=a.y; x[i][2]=a.z; x[i][3]=a.w;
        x[i][4]=b.x; x[i][5]=b.y; x[i][6]=b.z; x[i][7]=b.w;
    }
    __syncthreads();

    float A[2][8] = {};

    for (int c8 = 0; c8 < JC; c8 += 8) {
        #pragma unroll
        for (int u = 0; u < 8; ++u) {
            int t = c8 + u;
            int j = j0 + t;
            float4 a = sx[t * 2], b = sx[t * 2 + 1];
            bool hit[2];
            bool hany = false;
            #pragma unroll
            for (int i = 0; i < 2; ++i) {
                float d = fmaf(x[i][7], b.w, fmaf(x[i][6], b.z,
                          fmaf(x[i][5], b.y, fmaf(x[i][4], b.x,
                          fmaf(x[i][3], a.w, fmaf(x[i][2], a.z,
                          fmaf(x[i][1], a.y, x[i][0] * a.x)))))));
                hit[i] = (d * d >= 0.8f) && (j != r + i * RSTR);
                hany = hany || hit[i];
            }
            if (hany) {
                float4 u0 = si[t * 2], u1 = si[t * 2 + 1];
                #pragma unroll
                for (int i = 0; i < 2; ++i) {
                    if (hit[i]) {
                        A[i][0]+=u0.x; A[i][1]+=u0.y; A[i][2]+=u0.z; A[i][3]+=u0.w;
                        A[i][4]+=u1.x; A[i][5]+=u1.y; A[i][6]+=u1.z; A[i][7]+=u1.w;
                    }
                }
            }
        }
    }
    #pragma unroll
    for (int i = 0; i < 2; ++i) {
        float4* o = reinterpret_cast<float4*>(pns + ((size_t)(r + i * RSTR) * SEGS + seg) * 8);
        o[0] = make_float4(A[i][0], A[i][1], A[i][2], A[i][3]);
        o[1] = make_float4(A[i][4], A[i][5], A[i][6], A[i][7]);
    }
}

// ---- kernel 3: wide-parallel reduce + GNN relu + q/k proj; emits fp16 MFMA operand arrays ----
// qhp[row][16] = fp16 q (pre-scaled), dims 8-15 zero; khp[row][16] likewise;
// difT[dim][row] fp16, dims 8-15 rows zero.
template<int NSEG>
__global__ __launch_bounds__(256) void k_diff3(const float* __restrict__ pns,
                                               const float* __restrict__ gw,
                                               const float* __restrict__ gb,
                                               const float* __restrict__ rot,
                                               const float* __restrict__ ent,
                                               _Float16* __restrict__ qhp,
                                               _Float16* __restrict__ khp,
                                               _Float16* __restrict__ difT) {
    int tid = threadIdx.x;
    int sub = tid & 31;
    int row = blockIdx.x * 8 + (tid >> 5);
    float ns[8] = {0,0,0,0,0,0,0,0};
    #pragma unroll
    for (int it = 0; it < NSEG / 32; ++it) {
        int g = sub + it * 32;
        const float4* p = reinterpret_cast<const float4*>(pns + ((size_t)row * NSEG + g) * 8);
        float4 a = p[0], b = p[1];
        ns[0]+=a.x; ns[1]+=a.y; ns[2]+=a.z; ns[3]+=a.w;
        ns[4]+=b.x; ns[5]+=b.y; ns[6]+=b.z; ns[7]+=b.w;
    }
    #pragma unroll
    for (int msk = 1; msk <= 16; msk <<= 1) {
        #pragma unroll
        for (int e = 0; e < 8; ++e) ns[e] += __shfl_xor(ns[e], msk);
    }
    if (sub == 0) {
        float df[8];
        #pragma unroll
        for (int d = 0; d < 8; ++d) {
            float v = gb[d];
            #pragma unroll
            for (int e = 0; e < 8; ++e) v += ns[e] * gw[d * 8 + e];
            df[d] = fmaxf(v, 0.0f);
        }
        const float QSC = (float)(1.4426950408889634 / 2.8284271247461903); // log2(e)/sqrt(8)
        #pragma unroll
        for (int d = 0; d < 8; ++d) {
            float vq = 0.0f, vk = 0.0f;
            #pragma unroll
            for (int e = 0; e < 8; ++e) {
                vq += df[e] * rot[e * 8 + d];
                vk += df[e] * ent[e * 8 + d];
            }
            qhp[(size_t)row * 16 + d] = (_Float16)(vq * QSC);
            khp[(size_t)row * 16 + d] = (_Float16)vk;
            difT[(size_t)d * NN + row] = (_Float16)df[d];
        }
        #pragma unroll
        for (int d = 8; d < 16; ++d) {
            qhp[(size_t)row * 16 + d] = (_Float16)0.0f;
            khp[(size_t)row * 16 + d] = (_Float16)0.0f;
            difT[(size_t)d * NN + row] = (_Float16)0.0f;
        }
    }
}

// ---- kernel 4: MFMA flash attention. One wave = 16 queries x one key-segment. ----
// S^T = mfma(K, Q^T): lane holds scores for q=lane&15, keys=(lane>>4)*4+v  -> softmax lane-local.
// O^T = mfma(Dif^T, P^T): accumulates attended^T in same q-on-col layout.
template<int SEGS>
__global__ __launch_bounds__(256) void k_attn_m(const _Float16* __restrict__ qhp,
                                                const _Float16* __restrict__ khp,
                                                const _Float16* __restrict__ difT,
                                                float* __restrict__ pacc,
                                                float* __restrict__ pm,
                                                float* __restrict__ psum) {
    constexpr int JC = NN / SEGS;
    int tid = threadIdx.x;
    int lane = tid & 63;
    int w = tid >> 6;
    int qbase = (blockIdx.x * 4 + w) * 16;
    int seg = blockIdx.y;
    int j0 = seg * JC;
    int l15 = lane & 15;
    int kgrp = lane >> 4;                    // 0..3

    // Q^T operand: lane holds Q[qbase + l15][kgrp*4 .. +3]
    h4v qv = *reinterpret_cast<const h4v*>(qhp + (size_t)(qbase + l15) * 16 + kgrp * 4);

    float m = -3.0e38f, sum = 0.0f;
    f4v O = {0.0f, 0.0f, 0.0f, 0.0f};

    for (int t = 0; t < JC / 16; ++t) {
        int kb = j0 + t * 16;
        // K operand: lane holds K[kb + l15][kgrp*4 .. +3]   (dims >= 8 are zero-padded)
        h4v kv = *reinterpret_cast<const h4v*>(khp + (size_t)(kb + l15) * 16 + kgrp * 4);
        f4v s = __builtin_amdgcn_mfma_f32_16x16x16f16(kv, qv, (f4v){0.f,0.f,0.f,0.f}, 0, 0, 0);
        // s[v] = S^T[key = kgrp*4+v][q = l15]

        float tm = fmaxf(fmaxf(s[0], s[1]), fmaxf(s[2], s[3]));
        tm = fmaxf(tm, __shfl_xor(tm, 16));
        tm = fmaxf(tm, __shfl_xor(tm, 32));
        float mn = fmaxf(m, tm);
        float rs = fexp2(m - mn);            // first tile: exp2(-huge) = 0
        m = mn;
        float p0 = fexp2(s[0] - mn);
        float p1 = fexp2(s[1] - mn);
        float p2 = fexp2(s[2] - mn);
        float p3 = fexp2(s[3] - mn);
        sum = fmaf(sum, rs, (p0 + p1) + (p2 + p3));
        h4v pa = {(_Float16)p0, (_Float16)p1, (_Float16)p2, (_Float16)p3};

        // Dif^T operand: lane holds dif[key = kb + kgrp*4 .. +3][dim = l15]
        h4v dv = *reinterpret_cast<const h4v*>(difT + (size_t)l15 * NN + kb + kgrp * 4);
        O[0] *= rs; O[1] *= rs; O[2] *= rs; O[3] *= rs;
        O = __builtin_amdgcn_mfma_f32_16x16x16f16(dv, pa, O, 0, 0, 0);
        // O[v] = attended^T[dim = kgrp*4+v][q = l15]
    }

    // finalize sum across the 4 key-groups (m already uniform after tile-max reduce)
    sum += __shfl_xor(sum, 16);
    sum += __shfl_xor(sum, 32);

    size_t b = (size_t)(qbase + l15) * SEGS + seg;
    if (lane < 32) {
        // lanes 0-15: dims 0-3; lanes 16-31: dims 4-7
        float4* o = reinterpret_cast<float4*>(pacc + b * 8 + kgrp * 4);
        *o = make_float4(O[0], O[1], O[2], O[3]);
    }
    if (lane < 16) {
        pm[b] = m;
        psum[b] = sum;
    }
}

// ---- kernel 5: wide-parallel (32 thr/row) flash-merge + QCNN; coalesced reads (r18) ----
template<int NSEG>
__global__ __launch_bounds__(256) void k_merge3(const float* __restrict__ pacc,
                                                const float* __restrict__ pm,
                                                const float* __restrict__ psum,
                                                const float* __restrict__ qw0, const float* __restrict__ qb0,
                                                const float* __restrict__ qw1, const float* __restrict__ qb1,
                                                const float* __restrict__ qw2, const float* __restrict__ qb2,
                                                const float* __restrict__ qw3, const float* __restrict__ qb3,
                                                const float* __restrict__ qw4, const float* __restrict__ qb4,
                                                const float* __restrict__ qw5, const float* __restrict__ qb5,
                                                float* __restrict__ out) {
    int tid = threadIdx.x;
    int sub = tid & 31;
    int row = blockIdx.x * 8 + (tid >> 5);

    float m = -3.0e38f, T = 0.0f;
    float A[8] = {0,0,0,0,0,0,0,0};
    #pragma unroll
    for (int it = 0; it < NSEG / 32; ++it) {
        int g = sub + it * 32;
        size_t base = (size_t)row * NSEG + g;
        float mg = pm[base];
        float newm = fmaxf(m, mg);
        float cs = fexp2(m - newm);
        float cg = fexp2(mg - newm);
        T = fmaf(T, cs, psum[base] * cg);
        const float4* p = reinterpret_cast<const float4*>(pacc + base * 8);
        float4 a = p[0], b = p[1];
        A[0] = fmaf(A[0], cs, a.x * cg); A[1] = fmaf(A[1], cs, a.y * cg);
        A[2] = fmaf(A[2], cs, a.z * cg); A[3] = fmaf(A[3], cs, a.w * cg);
        A[4] = fmaf(A[4], cs, b.x * cg); A[5] = fmaf(A[5], cs, b.y * cg);
        A[6] = fmaf(A[6], cs, b.z * cg); A[7] = fmaf(A[7], cs, b.w * cg);
        m = newm;
    }
    #pragma unroll
    for (int msk = 1; msk <= 16; msk <<= 1) {
        float mo = __shfl_xor(m, msk);
        float To = __shfl_xor(T, msk);
        float Ao[8];
        #pragma unroll
        for (int e = 0; e < 8; ++e) Ao[e] = __shfl_xor(A[e], msk);
        float newm = fmaxf(m, mo);
        float cs = fexp2(m - newm);
        float co = fexp2(mo - newm);
        T = T * cs + To * co;
        #pragma unroll
        for (int e = 0; e < 8; ++e) A[e] = A[e] * cs + Ao[e] * co;
        m = newm;
    }

    if (sub == 0) {
        float invT = 1.0f / T;
        float h0[8];
        #pragma unroll
        for (int d = 0; d < 8; ++d) h0[d] = A[d] * invT;

        float h1[16];
        #pragma unroll
        for (int t = 0; t < 16; ++t) {
            float v = qb0[t];
            #pragma unroll
            for (int e = 0; e < 8; ++e) v += h0[e] * qw0[t * 8 + e];
            h1[t] = tanhf(v);
        }
        float h2x[16];
        #pragma unroll
        for (int t = 0; t < 16; ++t) {
            float v = qb1[t];
            #pragma unroll
            for (int e = 0; e < 16; ++e) v += h1[e] * qw1[t * 16 + e];
            h2x[t] = tanhf(v);
        }
        float h3[12];
        #pragma unroll
        for (int t = 0; t < 12; ++t) {
            float v = qb2[t];
            #pragma unroll
            for (int e = 0; e < 16; ++e) v += h2x[e] * qw2[t * 16 + e];
            h3[t] = tanhf(v);
        }
        float h4[8];
        #pragma unroll
        for (int t = 0; t < 8; ++t) {
            float v = qb3[t];
            #pragma unroll
            for (int e = 0; e < 12; ++e) v += h3[e] * qw3[t * 12 + e];
            h4[t] = tanhf(v);
        }
        float h5[4];
        #pragma unroll
        for (int t = 0; t < 4; ++t) {
            float v = qb4[t];
            #pragma unroll
            for (int e = 0; e < 8; ++e) v += h4[e] * qw4[t * 8 + e];
            h5[t] = tanhf(v);
        }
        float o = qb5[0];
        #pragma unroll
        for (int e = 0; e < 4; ++e) o += h5[e] * qw5[e];
        out[row] = 1.0f / (1.0f + expf(-o));
    }
}

extern "C" void kernel_launch(void* const* d_in, const int* in_sizes, int n_in,
                              void* d_out, int out_size, void* d_ws, size_t ws_size,
                              hipStream_t stream) {
    const float* in  = (const float*)d_in[0];
    const float* rot = (const float*)d_in[1];
    const float* ent = (const float*)d_in[2];
    const float* gw  = (const float*)d_in[3];
    const float* gb  = (const float*)d_in[4];
    const float* qw0 = (const float*)d_in[5];
    const float* qb0 = (const float*)d_in[6];
    const float* qw1 = (const float*)d_in[7];
    const float* qb1 = (const float*)d_in[8];
    const float* qw2 = (const float*)d_in[9];
    const float* qb2 = (const float*)d_in[10];
    const float* qw3 = (const float*)d_in[11];
    const float* qb3 = (const float*)d_in[12];
    const float* qw4 = (const float*)d_in[13];
    const float* qb4 = (const float*)d_in[14];
    const float* qw5 = (const float*)d_in[15];
    const float* qb5 = (const float*)d_in[16];

    auto need = [](int nseg) { return ((size_t)NN * 8 * 4 + (size_t)nseg * NN * 18) * 4; };
    const int nseg = (ws_size >= need(64)) ? 64 : 32;

    float* ws = (float*)d_ws;
    size_t off = 0;
    float* xn   = ws + off; off += (size_t)NN * 8;
    float* pns  = ws + off; off += (size_t)nseg * NN * 8;
    _Float16* qhp  = (_Float16*)(ws + off); off += (size_t)NN * 8;  // NN x 16 halves
    _Float16* khp  = (_Float16*)(ws + off); off += (size_t)NN * 8;
    _Float16* difT = (_Float16*)(ws + off); off += (size_t)NN * 8;  // 16 dims x NN halves
    float* pacc = ws + off; off += (size_t)nseg * NN * 8;
    float* pm   = ws + off; off += (size_t)nseg * NN;
    float* psum = ws + off; off += (size_t)nseg * NN;

    dim3 blk(256);
    k_norm<<<dim3(NN / 256), blk, 0, stream>>>(in, xn);
    if (nseg == 64) {
        k_adj_t<64><<<dim3(NN / 2 / 256, 64), blk, 0, stream>>>(xn, in, pns);
        k_diff3<64><<<dim3(NN / 8), blk, 0, stream>>>(pns, gw, gb, rot, ent, qhp, khp, difT);
        k_attn_m<64><<<dim3(NN / 64, 64), blk, 0, stream>>>(qhp, khp, difT, pacc, pm, psum);
        k_merge3<64><<<dim3(NN / 8), blk, 0, stream>>>(pacc, pm, psum,
                                                       qw0, qb0, qw1, qb1, qw2, qb2,
                                                       qw3, qb3, qw4, qb4, qw5, qb5,
                                                       (float*)d_out);
    } else {
        k_adj_t<32><<<dim3(NN / 2 / 256, 32), blk, 0, stream>>>(xn, in, pns);
        k_diff3<32><<<dim3(NN / 8), blk, 0, stream>>>(pns, gw, gb, rot, ent, qhp, khp, difT);
        k_attn_m<32><<<dim3(NN / 64, 32), blk, 0, stream>>>(qhp, khp, difT, pacc, pm, psum);
        k_merge3<32><<<dim3(NN / 8), blk, 0, stream>>>(pacc, pm, psum,
                                                       qw0, qb0, qw1, qb1, qw2, qb2,
                                                       qw3, qb3, qw4, qb4, qw5, qb5,
                                                       (float*)d_out);
    }
}

// Round 21
// 106.796 us; speedup vs baseline: 1.0159x; 1.0159x over previous
//
#include <hip/hip_runtime.h>
#include <math.h>

#define NN 8192

typedef _Float16 h4v __attribute__((ext_vector_type(4)));
typedef float f4v __attribute__((ext_vector_type(4)));

__device__ __forceinline__ float fexp2(float x) {
    float r;
    asm("v_exp_f32 %0, %1" : "=v"(r) : "v"(x));
    return r;
}

// ---------------- kernel 1: row normalize ----------------
__global__ __launch_bounds__(256) void k_norm(const float* __restrict__ in,
                                              float* __restrict__ xn) {
    int r = blockIdx.x * 256 + threadIdx.x;
    const float4* p = reinterpret_cast<const float4*>(in + (size_t)r * 8);
    float4 a = p[0], b = p[1];
    float ss = a.x*a.x + a.y*a.y + a.z*a.z + a.w*a.w
             + b.x*b.x + b.y*b.y + b.z*b.z + b.w*b.w;
    float inv = 1.0f / (sqrtf(ss) + 1e-12f);
    a.x *= inv; a.y *= inv; a.z *= inv; a.w *= inv;
    b.x *= inv; b.y *= inv; b.z *= inv; b.w *= inv;
    float4* o = reinterpret_cast<float4*>(xn + (size_t)r * 8);
    o[0] = a; o[1] = b;
}

// ---- kernel 2: adjacency row-sum; LDS-staged f32 (threshold exact); seg-fastest out (r18) ----
template<int SEGS>
__global__ __launch_bounds__(256) void k_adj_t(const float* __restrict__ xn,
                                               const float* __restrict__ in,
                                               float* __restrict__ pns) {
    constexpr int JC = NN / SEGS;
    constexpr int RSTR = NN / 2;
    __shared__ float4 sx[JC * 2];
    __shared__ float4 si[JC * 2];
    int tid = threadIdx.x;
    int r = blockIdx.x * 256 + tid;          // [0, NN/2)
    int seg = blockIdx.y;
    int j0 = seg * JC;

    for (int idx = tid; idx < JC * 2; idx += 256) {
        sx[idx] = reinterpret_cast<const float4*>(xn + (size_t)j0 * 8)[idx];
        si[idx] = reinterpret_cast<const float4*>(in + (size_t)j0 * 8)[idx];
    }
    float x[2][8];
    #pragma unroll
    for (int i = 0; i < 2; ++i) {
        const float4* xp = reinterpret_cast<const float4*>(xn + (size_t)(r + i * RSTR) * 8);
        float4 a = xp[0], b = xp[1];
        x[i][0]=a.x; x[i][1]=a.y; x[i][2]=a.z; x[i][3]=a.w;
        x[i][4]=b.x; x[i][5]=b.y; x[i][6]=b.z; x[i][7]=b.w;
    }
    __syncthreads();

    float A[2][8] = {};

    for (int c8 = 0; c8 < JC; c8 += 8) {
        #pragma unroll
        for (int u = 0; u < 8; ++u) {
            int t = c8 + u;
            int j = j0 + t;
            float4 a = sx[t * 2], b = sx[t * 2 + 1];
            bool hit[2];
            bool hany = false;
            #pragma unroll
            for (int i = 0; i < 2; ++i) {
                float d = fmaf(x[i][7], b.w, fmaf(x[i][6], b.z,
                          fmaf(x[i][5], b.y, fmaf(x[i][4], b.x,
                          fmaf(x[i][3], a.w, fmaf(x[i][2], a.z,
                          fmaf(x[i][1], a.y, x[i][0] * a.x)))))));
                hit[i] = (d * d >= 0.8f) && (j != r + i * RSTR);
                hany = hany || hit[i];
            }
            if (hany) {
                float4 u0 = si[t * 2], u1 = si[t * 2 + 1];
                #pragma unroll
                for (int i = 0; i < 2; ++i) {
                    if (hit[i]) {
                        A[i][0]+=u0.x; A[i][1]+=u0.y; A[i][2]+=u0.z; A[i][3]+=u0.w;
                        A[i][4]+=u1.x; A[i][5]+=u1.y; A[i][6]+=u1.z; A[i][7]+=u1.w;
                    }
                }
            }
        }
    }
    #pragma unroll
    for (int i = 0; i < 2; ++i) {
        float4* o = reinterpret_cast<float4*>(pns + ((size_t)(r + i * RSTR) * SEGS + seg) * 8);
        o[0] = make_float4(A[i][0], A[i][1], A[i][2], A[i][3]);
        o[1] = make_float4(A[i][4], A[i][5], A[i][6], A[i][7]);
    }
}

// ---- kernel 3: wide-parallel reduce + GNN relu + q/k proj; emits fp16 MFMA operand arrays ----
template<int NSEG>
__global__ __launch_bounds__(256) void k_diff3(const float* __restrict__ pns,
                                               const float* __restrict__ gw,
                                               const float* __restrict__ gb,
                                               const float* __restrict__ rot,
                                               const float* __restrict__ ent,
                                               _Float16* __restrict__ qhp,
                                               _Float16* __restrict__ khp,
                                               _Float16* __restrict__ difT) {
    int tid = threadIdx.x;
    int sub = tid & 31;
    int row = blockIdx.x * 8 + (tid >> 5);
    float ns[8] = {0,0,0,0,0,0,0,0};
    #pragma unroll
    for (int it = 0; it < NSEG / 32; ++it) {
        int g = sub + it * 32;
        const float4* p = reinterpret_cast<const float4*>(pns + ((size_t)row * NSEG + g) * 8);
        float4 a = p[0], b = p[1];
        ns[0]+=a.x; ns[1]+=a.y; ns[2]+=a.z; ns[3]+=a.w;
        ns[4]+=b.x; ns[5]+=b.y; ns[6]+=b.z; ns[7]+=b.w;
    }
    #pragma unroll
    for (int msk = 1; msk <= 16; msk <<= 1) {
        #pragma unroll
        for (int e = 0; e < 8; ++e) ns[e] += __shfl_xor(ns[e], msk);
    }
    if (sub == 0) {
        float df[8];
        #pragma unroll
        for (int d = 0; d < 8; ++d) {
            float v = gb[d];
            #pragma unroll
            for (int e = 0; e < 8; ++e) v += ns[e] * gw[d * 8 + e];
            df[d] = fmaxf(v, 0.0f);
        }
        const float QSC = (float)(1.4426950408889634 / 2.8284271247461903); // log2(e)/sqrt(8)
        #pragma unroll
        for (int d = 0; d < 8; ++d) {
            float vq = 0.0f, vk = 0.0f;
            #pragma unroll
            for (int e = 0; e < 8; ++e) {
                vq += df[e] * rot[e * 8 + d];
                vk += df[e] * ent[e * 8 + d];
            }
            qhp[(size_t)row * 16 + d] = (_Float16)(vq * QSC);
            khp[(size_t)row * 16 + d] = (_Float16)vk;
            difT[(size_t)d * NN + row] = (_Float16)df[d];
        }
        #pragma unroll
        for (int d = 8; d < 16; ++d) {
            qhp[(size_t)row * 16 + d] = (_Float16)0.0f;
            khp[(size_t)row * 16 + d] = (_Float16)0.0f;
            difT[(size_t)d * NN + row] = (_Float16)0.0f;
        }
    }
}

// ---- kernel 4: MFMA flash attention, two-pass per 8-tile chunk ----
// Pass 1: prefetch 8 tiles' operands into registers, 8 INDEPENDENT S-MFMAs, one chunk max.
// Pass 2: 32 independent exp2 + 8 accumulate-MFMAs. No per-tile serial softmax chain.
template<int SEGS>
__global__ __launch_bounds__(256) void k_attn_m(const _Float16* __restrict__ qhp,
                                                const _Float16* __restrict__ khp,
                                                const _Float16* __restrict__ difT,
                                                float* __restrict__ pacc,
                                                float* __restrict__ pm,
                                                float* __restrict__ psum) {
    constexpr int JC = NN / SEGS;
    constexpr int TILES = JC / 16;
    int tid = threadIdx.x;
    int lane = tid & 63;
    int w = tid >> 6;
    int qbase = (blockIdx.x * 4 + w) * 16;
    int seg = blockIdx.y;
    int j0 = seg * JC;
    int l15 = lane & 15;
    int kgrp = lane >> 4;                    // 0..3

    h4v qv = *reinterpret_cast<const h4v*>(qhp + (size_t)(qbase + l15) * 16 + kgrp * 4);

    float m = -3.0e38f, sum = 0.0f;
    f4v O = {0.0f, 0.0f, 0.0f, 0.0f};

    for (int c = 0; c < TILES; c += 8) {
        // pass 0: prefetch all 8 tiles' operands (explicit arrays force hoisted loads)
        h4v kvs[8], dvs[8];
        #pragma unroll
        for (int t = 0; t < 8; ++t) {
            int kb = j0 + (c + t) * 16;
            kvs[t] = *reinterpret_cast<const h4v*>(khp + (size_t)(kb + l15) * 16 + kgrp * 4);
            dvs[t] = *reinterpret_cast<const h4v*>(difT + (size_t)l15 * NN + kb + kgrp * 4);
        }
        // pass 1: 8 independent score MFMAs
        f4v s[8];
        #pragma unroll
        for (int t = 0; t < 8; ++t)
            s[t] = __builtin_amdgcn_mfma_f32_16x16x16f16(kvs[t], qv, (f4v){0.f,0.f,0.f,0.f}, 0, 0, 0);
        // chunk max (per-lane tree, then 2 shfls)
        float tm = -3.0e38f;
        #pragma unroll
        for (int t = 0; t < 8; ++t)
            tm = fmaxf(tm, fmaxf(fmaxf(s[t][0], s[t][1]), fmaxf(s[t][2], s[t][3])));
        tm = fmaxf(tm, __shfl_xor(tm, 16));
        tm = fmaxf(tm, __shfl_xor(tm, 32));
        float mn = fmaxf(m, tm);
        float rs = fexp2(m - mn);            // first chunk: exp2(-huge)=0
        m = mn;
        sum *= rs;
        O[0] *= rs; O[1] *= rs; O[2] *= rs; O[3] *= rs;
        // pass 2: independent exp2s + accumulate MFMAs
        #pragma unroll
        for (int t = 0; t < 8; ++t) {
            float p0 = fexp2(s[t][0] - m);
            float p1 = fexp2(s[t][1] - m);
            float p2 = fexp2(s[t][2] - m);
            float p3 = fexp2(s[t][3] - m);
            sum += (p0 + p1) + (p2 + p3);
            h4v pa = {(_Float16)p0, (_Float16)p1, (_Float16)p2, (_Float16)p3};
            O = __builtin_amdgcn_mfma_f32_16x16x16f16(dvs[t], pa, O, 0, 0, 0);
        }
    }

    sum += __shfl_xor(sum, 16);
    sum += __shfl_xor(sum, 32);

    size_t b = (size_t)(qbase + l15) * SEGS + seg;
    if (lane < 32) {
        float4* o = reinterpret_cast<float4*>(pacc + b * 8 + kgrp * 4);
        *o = make_float4(O[0], O[1], O[2], O[3]);
    }
    if (lane < 16) {
        pm[b] = m;
        psum[b] = sum;
    }
}

// ---- kernel 5: wide-parallel (32 thr/row) flash-merge + QCNN; coalesced reads (r18) ----
template<int NSEG>
__global__ __launch_bounds__(256) void k_merge3(const float* __restrict__ pacc,
                                                const float* __restrict__ pm,
                                                const float* __restrict__ psum,
                                                const float* __restrict__ qw0, const float* __restrict__ qb0,
                                                const float* __restrict__ qw1, const float* __restrict__ qb1,
                                                const float* __restrict__ qw2, const float* __restrict__ qb2,
                                                const float* __restrict__ qw3, const float* __restrict__ qb3,
                                                const float* __restrict__ qw4, const float* __restrict__ qb4,
                                                const float* __restrict__ qw5, const float* __restrict__ qb5,
                                                float* __restrict__ out) {
    int tid = threadIdx.x;
    int sub = tid & 31;
    int row = blockIdx.x * 8 + (tid >> 5);

    float m = -3.0e38f, T = 0.0f;
    float A[8] = {0,0,0,0,0,0,0,0};
    #pragma unroll
    for (int it = 0; it < NSEG / 32; ++it) {
        int g = sub + it * 32;
        size_t base = (size_t)row * NSEG + g;
        float mg = pm[base];
        float newm = fmaxf(m, mg);
        float cs = fexp2(m - newm);
        float cg = fexp2(mg - newm);
        T = fmaf(T, cs, psum[base] * cg);
        const float4* p = reinterpret_cast<const float4*>(pacc + base * 8);
        float4 a = p[0], b = p[1];
        A[0] = fmaf(A[0], cs, a.x * cg); A[1] = fmaf(A[1], cs, a.y * cg);
        A[2] = fmaf(A[2], cs, a.z * cg); A[3] = fmaf(A[3], cs, a.w * cg);
        A[4] = fmaf(A[4], cs, b.x * cg); A[5] = fmaf(A[5], cs, b.y * cg);
        A[6] = fmaf(A[6], cs, b.z * cg); A[7] = fmaf(A[7], cs, b.w * cg);
        m = newm;
    }
    #pragma unroll
    for (int msk = 1; msk <= 16; msk <<= 1) {
        float mo = __shfl_xor(m, msk);
        float To = __shfl_xor(T, msk);
        float Ao[8];
        #pragma unroll
        for (int e = 0; e < 8; ++e) Ao[e] = __shfl_xor(A[e], msk);
        float newm = fmaxf(m, mo);
        float cs = fexp2(m - newm);
        float co = fexp2(mo - newm);
        T = T * cs + To * co;
        #pragma unroll
        for (int e = 0; e < 8; ++e) A[e] = A[e] * cs + Ao[e] * co;
        m = newm;
    }

    if (sub == 0) {
        float invT = 1.0f / T;
        float h0[8];
        #pragma unroll
        for (int d = 0; d < 8; ++d) h0[d] = A[d] * invT;

        float h1[16];
        #pragma unroll
        for (int t = 0; t < 16; ++t) {
            float v = qb0[t];
            #pragma unroll
            for (int e = 0; e < 8; ++e) v += h0[e] * qw0[t * 8 + e];
            h1[t] = tanhf(v);
        }
        float h2x[16];
        #pragma unroll
        for (int t = 0; t < 16; ++t) {
            float v = qb1[t];
            #pragma unroll
            for (int e = 0; e < 16; ++e) v += h1[e] * qw1[t * 16 + e];
            h2x[t] = tanhf(v);
        }
        float h3[12];
        #pragma unroll
        for (int t = 0; t < 12; ++t) {
            float v = qb2[t];
            #pragma unroll
            for (int e = 0; e < 16; ++e) v += h2x[e] * qw2[t * 16 + e];
            h3[t] = tanhf(v);
        }
        float h4[8];
        #pragma unroll
        for (int t = 0; t < 8; ++t) {
            float v = qb3[t];
            #pragma unroll
            for (int e = 0; e < 12; ++e) v += h3[e] * qw3[t * 12 + e];
            h4[t] = tanhf(v);
        }
        float h5[4];
        #pragma unroll
        for (int t = 0; t < 4; ++t) {
            float v = qb4[t];
            #pragma unroll
            for (int e = 0; e < 8; ++e) v += h4[e] * qw4[t * 8 + e];
            h5[t] = tanhf(v);
        }
        float o = qb5[0];
        #pragma unroll
        for (int e = 0; e < 4; ++e) o += h5[e] * qw5[e];
        out[row] = 1.0f / (1.0f + expf(-o));
    }
}

extern "C" void kernel_launch(void* const* d_in, const int* in_sizes, int n_in,
                              void* d_out, int out_size, void* d_ws, size_t ws_size,
                              hipStream_t stream) {
    const float* in  = (const float*)d_in[0];
    const float* rot = (const float*)d_in[1];
    const float* ent = (const float*)d_in[2];
    const float* gw  = (const float*)d_in[3];
    const float* gb  = (const float*)d_in[4];
    const float* qw0 = (const float*)d_in[5];
    const float* qb0 = (const float*)d_in[6];
    const float* qw1 = (const float*)d_in[7];
    const float* qb1 = (const float*)d_in[8];
    const float* qw2 = (const float*)d_in[9];
    const float* qb2 = (const float*)d_in[10];
    const float* qw3 = (const float*)d_in[11];
    const float* qb3 = (const float*)d_in[12];
    const float* qw4 = (const float*)d_in[13];
    const float* qb4 = (const float*)d_in[14];
    const float* qw5 = (const float*)d_in[15];
    const float* qb5 = (const float*)d_in[16];

    auto need = [](int nseg) { return ((size_t)NN * 8 * 4 + (size_t)nseg * NN * 18) * 4; };
    const int nseg = (ws_size >= need(64)) ? 64 : 32;

    float* ws = (float*)d_ws;
    size_t off = 0;
    float* xn   = ws + off; off += (size_t)NN * 8;
    float* pns  = ws + off; off += (size_t)nseg * NN * 8;
    _Float16* qhp  = (_Float16*)(ws + off); off += (size_t)NN * 8;  // NN x 16 halves
    _Float16* khp  = (_Float16*)(ws + off); off += (size_t)NN * 8;
    _Float16* difT = (_Float16*)(ws + off); off += (size_t)NN * 8;  // 16 dims x NN halves
    float* pacc = ws + off; off += (size_t)nseg * NN * 8;
    float* pm   = ws + off; off += (size_t)nseg * NN;
    float* psum = ws + off; off += (size_t)nseg * NN;

    dim3 blk(256);
    k_norm<<<dim3(NN / 256), blk, 0, stream>>>(in, xn);
    if (nseg == 64) {
        k_adj_t<64><<<dim3(NN / 2 / 256, 64), blk, 0, stream>>>(xn, in, pns);
        k_diff3<64><<<dim3(NN / 8), blk, 0, stream>>>(pns, gw, gb, rot, ent, qhp, khp, difT);
        k_attn_m<64><<<dim3(NN / 64, 64), blk, 0, stream>>>(qhp, khp, difT, pacc, pm, psum);
        k_merge3<64><<<dim3(NN / 8), blk, 0, stream>>>(pacc, pm, psum,
                                                       qw0, qb0, qw1, qb1, qw2, qb2,
                                                       qw3, qb3, qw4, qb4, qw5, qb5,
                                                       (float*)d_out);
    } else {
        k_adj_t<32><<<dim3(NN / 2 / 256, 32), blk, 0, stream>>>(xn, in, pns);
        k_diff3<32><<<dim3(NN / 8), blk, 0, stream>>>(pns, gw, gb, rot, ent, qhp, khp, difT);
        k_attn_m<32><<<dim3(NN / 64, 32), blk, 0, stream>>>(qhp, khp, difT, pacc, pm, psum);
        k_merge3<32><<<dim3(NN / 8), blk, 0, stream>>>(pacc, pm, psum,
                                                       qw0, qb0, qw1, qb1, qw2, qb2,
                                                       qw3, qb3, qw4, qb4, qw5, qb5,
                                                       (float*)d_out);
    }
}

// Round 22
// 100.745 us; speedup vs baseline: 1.0769x; 1.0601x over previous
//
#include <hip/hip_runtime.h>
#include <math.h>

#define NN 8192

__device__ __forceinline__ float fexp2(float x) {
    float r;
    asm("v_exp_f32 %0, %1" : "=v"(r) : "v"(x));
    return r;
}

// ---------------- kernel 1: row normalize ----------------
__global__ __launch_bounds__(256) void k_norm(const float* __restrict__ in,
                                              float* __restrict__ xn) {
    int r = blockIdx.x * 256 + threadIdx.x;
    const float4* p = reinterpret_cast<const float4*>(in + (size_t)r * 8);
    float4 a = p[0], b = p[1];
    float ss = a.x*a.x + a.y*a.y + a.z*a.z + a.w*a.w
             + b.x*b.x + b.y*b.y + b.z*b.z + b.w*b.w;
    float inv = 1.0f / (sqrtf(ss) + 1e-12f);
    a.x *= inv; a.y *= inv; a.z *= inv; a.w *= inv;
    b.x *= inv; b.y *= inv; b.z *= inv; b.w *= inv;
    float4* o = reinterpret_cast<float4*>(xn + (size_t)r * 8);
    o[0] = a; o[1] = b;
}

// ---- kernel 2: adjacency row-sum; LDS-staged f32 (threshold exact); seg-fastest out ----
template<int SEGS>
__global__ __launch_bounds__(256) void k_adj_t(const float* __restrict__ xn,
                                               const float* __restrict__ in,
                                               float* __restrict__ pns) {
    constexpr int JC = NN / SEGS;
    constexpr int RSTR = NN / 2;
    __shared__ float4 sx[JC * 2];
    __shared__ float4 si[JC * 2];
    int tid = threadIdx.x;
    int r = blockIdx.x * 256 + tid;          // [0, NN/2)
    int seg = blockIdx.y;
    int j0 = seg * JC;

    for (int idx = tid; idx < JC * 2; idx += 256) {
        sx[idx] = reinterpret_cast<const float4*>(xn + (size_t)j0 * 8)[idx];
        si[idx] = reinterpret_cast<const float4*>(in + (size_t)j0 * 8)[idx];
    }
    float x[2][8];
    #pragma unroll
    for (int i = 0; i < 2; ++i) {
        const float4* xp = reinterpret_cast<const float4*>(xn + (size_t)(r + i * RSTR) * 8);
        float4 a = xp[0], b = xp[1];
        x[i][0]=a.x; x[i][1]=a.y; x[i][2]=a.z; x[i][3]=a.w;
        x[i][4]=b.x; x[i][5]=b.y; x[i][6]=b.z; x[i][7]=b.w;
    }
    __syncthreads();

    float A[2][8] = {};

    for (int c8 = 0; c8 < JC; c8 += 8) {
        #pragma unroll
        for (int u = 0; u < 8; ++u) {
            int t = c8 + u;
            int j = j0 + t;
            float4 a = sx[t * 2], b = sx[t * 2 + 1];
            bool hit[2];
            bool hany = false;
            #pragma unroll
            for (int i = 0; i < 2; ++i) {
                float d = fmaf(x[i][7], b.w, fmaf(x[i][6], b.z,
                          fmaf(x[i][5], b.y, fmaf(x[i][4], b.x,
                          fmaf(x[i][3], a.w, fmaf(x[i][2], a.z,
                          fmaf(x[i][1], a.y, x[i][0] * a.x)))))));
                hit[i] = (d * d >= 0.8f) && (j != r + i * RSTR);
                hany = hany || hit[i];
            }
            if (hany) {
                float4 u0 = si[t * 2], u1 = si[t * 2 + 1];
                #pragma unroll
                for (int i = 0; i < 2; ++i) {
                    if (hit[i]) {
                        A[i][0]+=u0.x; A[i][1]+=u0.y; A[i][2]+=u0.z; A[i][3]+=u0.w;
                        A[i][4]+=u1.x; A[i][5]+=u1.y; A[i][6]+=u1.z; A[i][7]+=u1.w;
                    }
                }
            }
        }
    }
    #pragma unroll
    for (int i = 0; i < 2; ++i) {
        // segment-fastest layout: pns[row][seg][8]
        float4* o = reinterpret_cast<float4*>(pns + ((size_t)(r + i * RSTR) * SEGS + seg) * 8);
        o[0] = make_float4(A[i][0], A[i][1], A[i][2], A[i][3]);
        o[1] = make_float4(A[i][4], A[i][5], A[i][6], A[i][7]);
    }
}

// ---- kernel 3: wide-parallel (32 thr/row) reduce + GNN relu + q/k projections ----
// pns[row][seg][8]: lanes 0..31 read consecutive segments -> contiguous 1KB burst.
template<int NSEG>
__global__ __launch_bounds__(256) void k_diff3(const float* __restrict__ pns,
                                               const float* __restrict__ gw,
                                               const float* __restrict__ gb,
                                               const float* __restrict__ rot,
                                               const float* __restrict__ ent,
                                               float* __restrict__ dif,
                                               float* __restrict__ qsb,
                                               float* __restrict__ kkb) {
    int tid = threadIdx.x;
    int sub = tid & 31;
    int row = blockIdx.x * 8 + (tid >> 5);
    float ns[8] = {0,0,0,0,0,0,0,0};
    #pragma unroll
    for (int it = 0; it < NSEG / 32; ++it) {
        int g = sub + it * 32;
        const float4* p = reinterpret_cast<const float4*>(pns + ((size_t)row * NSEG + g) * 8);
        float4 a = p[0], b = p[1];
        ns[0]+=a.x; ns[1]+=a.y; ns[2]+=a.z; ns[3]+=a.w;
        ns[4]+=b.x; ns[5]+=b.y; ns[6]+=b.z; ns[7]+=b.w;
    }
    #pragma unroll
    for (int msk = 1; msk <= 16; msk <<= 1) {
        #pragma unroll
        for (int e = 0; e < 8; ++e) ns[e] += __shfl_xor(ns[e], msk);
    }
    if (sub == 0) {
        float df[8];
        #pragma unroll
        for (int d = 0; d < 8; ++d) {
            float v = gb[d];
            #pragma unroll
            for (int e = 0; e < 8; ++e) v += ns[e] * gw[d * 8 + e];
            df[d] = fmaxf(v, 0.0f);
        }
        const float QSC = (float)(1.4426950408889634 / 2.8284271247461903); // log2(e)/sqrt(8)
        #pragma unroll
        for (int d = 0; d < 8; ++d) {
            float vq = 0.0f, vk = 0.0f;
            #pragma unroll
            for (int e = 0; e < 8; ++e) {
                vq += df[e] * rot[e * 8 + d];
                vk += df[e] * ent[e * 8 + d];
            }
            qsb[(size_t)row * 8 + d] = vq * QSC;
            kkb[(size_t)row * 8 + d] = vk;
        }
        float4* o = reinterpret_cast<float4*>(dif + (size_t)row * 8);
        o[0] = make_float4(df[0], df[1], df[2], df[3]);
        o[1] = make_float4(df[4], df[5], df[6], df[7]);
    }
}

// ---- kernel 4: chunked-flash attention; LDS-staged, 2 rows/thread; seg-fastest partials ----
template<int SEGS>
__global__ __launch_bounds__(256) void k_attn_t(const float* __restrict__ qsb,
                                                const float* __restrict__ kkb,
                                                const float* __restrict__ dif,
                                                float* __restrict__ pacc,
                                                float* __restrict__ pm,
                                                float* __restrict__ psum) {
    constexpr int JC = NN / SEGS;
    constexpr int RSTR = NN / 2;
    __shared__ float4 sk[JC * 2];
    __shared__ float4 sd[JC * 2];
    int tid = threadIdx.x;
    int r = blockIdx.x * 256 + tid;          // [0, NN/2)
    int seg = blockIdx.y;
    int j0 = seg * JC;

    for (int idx = tid; idx < JC * 2; idx += 256) {
        sk[idx] = reinterpret_cast<const float4*>(kkb + (size_t)j0 * 8)[idx];
        sd[idx] = reinterpret_cast<const float4*>(dif + (size_t)j0 * 8)[idx];
    }
    float q[2][8];
    #pragma unroll
    for (int i = 0; i < 2; ++i) {
        const float4* qp = reinterpret_cast<const float4*>(qsb + (size_t)(r + i * RSTR) * 8);
        float4 a = qp[0], b = qp[1];
        q[i][0]=a.x; q[i][1]=a.y; q[i][2]=a.z; q[i][3]=a.w;
        q[i][4]=b.x; q[i][5]=b.y; q[i][6]=b.z; q[i][7]=b.w;
    }
    __syncthreads();

    float m[2], sum[2];
    float A[2][8] = {};
    #pragma unroll
    for (int i = 0; i < 2; ++i) { m[i] = -__builtin_huge_valf(); sum[i] = 0.0f; }

    for (int c8 = 0; c8 < JC; c8 += 8) {
        float s[2][8];
        #pragma unroll
        for (int u = 0; u < 8; ++u) {
            int t = c8 + u;
            float4 ka = sk[t * 2], kb = sk[t * 2 + 1];
            #pragma unroll
            for (int i = 0; i < 2; ++i) {
                s[i][u] = fmaf(q[i][7], kb.w, fmaf(q[i][6], kb.z,
                          fmaf(q[i][5], kb.y, fmaf(q[i][4], kb.x,
                          fmaf(q[i][3], ka.w, fmaf(q[i][2], ka.z,
                          fmaf(q[i][1], ka.y, q[i][0] * ka.x)))))));
            }
        }
        #pragma unroll
        for (int i = 0; i < 2; ++i) {
            float cm = fmaxf(fmaxf(fmaxf(s[i][0], s[i][1]), fmaxf(s[i][2], s[i][3])),
                             fmaxf(fmaxf(s[i][4], s[i][5]), fmaxf(s[i][6], s[i][7])));
            float mn = fmaxf(m[i], cm);
            float rs = fexp2(m[i] - mn);     // first chunk: exp2(-inf)=0
            m[i] = mn;
            sum[i] *= rs;
            #pragma unroll
            for (int e = 0; e < 8; ++e) A[i][e] *= rs;
        }
        #pragma unroll
        for (int u = 0; u < 8; ++u) {
            int t = c8 + u;
            float4 da = sd[t * 2], db = sd[t * 2 + 1];
            #pragma unroll
            for (int i = 0; i < 2; ++i) {
                float p = fexp2(s[i][u] - m[i]);
                sum[i] += p;
                A[i][0] = fmaf(p, da.x, A[i][0]); A[i][1] = fmaf(p, da.y, A[i][1]);
                A[i][2] = fmaf(p, da.z, A[i][2]); A[i][3] = fmaf(p, da.w, A[i][3]);
                A[i][4] = fmaf(p, db.x, A[i][4]); A[i][5] = fmaf(p, db.y, A[i][5]);
                A[i][6] = fmaf(p, db.z, A[i][6]); A[i][7] = fmaf(p, db.w, A[i][7]);
            }
        }
    }

    #pragma unroll
    for (int i = 0; i < 2; ++i) {
        // segment-fastest layout: pacc[row][seg][8], pm/psum[row][seg]
        size_t b = (size_t)(r + i * RSTR) * SEGS + seg;
        float4* o = reinterpret_cast<float4*>(pacc + b * 8);
        o[0] = make_float4(A[i][0], A[i][1], A[i][2], A[i][3]);
        o[1] = make_float4(A[i][4], A[i][5], A[i][6], A[i][7]);
        pm[b] = m[i];
        psum[b] = sum[i];
    }
}

// ---- kernel 5: wide-parallel (32 thr/row) flash-merge + QCNN; coalesced reads ----
template<int NSEG>
__global__ __launch_bounds__(256) void k_merge3(const float* __restrict__ pacc,
                                                const float* __restrict__ pm,
                                                const float* __restrict__ psum,
                                                const float* __restrict__ qw0, const float* __restrict__ qb0,
                                                const float* __restrict__ qw1, const float* __restrict__ qb1,
                                                const float* __restrict__ qw2, const float* __restrict__ qb2,
                                                const float* __restrict__ qw3, const float* __restrict__ qb3,
                                                const float* __restrict__ qw4, const float* __restrict__ qb4,
                                                const float* __restrict__ qw5, const float* __restrict__ qb5,
                                                float* __restrict__ out) {
    int tid = threadIdx.x;
    int sub = tid & 31;
    int row = blockIdx.x * 8 + (tid >> 5);

    // local flash-merge of this sub's segments (finite init avoids NaN in butterfly)
    float m = -3.0e38f, T = 0.0f;
    float A[8] = {0,0,0,0,0,0,0,0};
    #pragma unroll
    for (int it = 0; it < NSEG / 32; ++it) {
        int g = sub + it * 32;
        size_t base = (size_t)row * NSEG + g;
        float mg = pm[base];
        float newm = fmaxf(m, mg);
        float cs = fexp2(m - newm);
        float cg = fexp2(mg - newm);
        T = fmaf(T, cs, psum[base] * cg);
        const float4* p = reinterpret_cast<const float4*>(pacc + base * 8);
        float4 a = p[0], b = p[1];
        A[0] = fmaf(A[0], cs, a.x * cg); A[1] = fmaf(A[1], cs, a.y * cg);
        A[2] = fmaf(A[2], cs, a.z * cg); A[3] = fmaf(A[3], cs, a.w * cg);
        A[4] = fmaf(A[4], cs, b.x * cg); A[5] = fmaf(A[5], cs, b.y * cg);
        A[6] = fmaf(A[6], cs, b.z * cg); A[7] = fmaf(A[7], cs, b.w * cg);
        m = newm;
    }
    // butterfly flash-combine across the 32 cooperating lanes
    #pragma unroll
    for (int msk = 1; msk <= 16; msk <<= 1) {
        float mo = __shfl_xor(m, msk);
        float To = __shfl_xor(T, msk);
        float Ao[8];
        #pragma unroll
        for (int e = 0; e < 8; ++e) Ao[e] = __shfl_xor(A[e], msk);
        float newm = fmaxf(m, mo);
        float cs = fexp2(m - newm);
        float co = fexp2(mo - newm);
        T = T * cs + To * co;
        #pragma unroll
        for (int e = 0; e < 8; ++e) A[e] = A[e] * cs + Ao[e] * co;
        m = newm;
    }

    if (sub == 0) {
        float invT = 1.0f / T;
        float h0[8];
        #pragma unroll
        for (int d = 0; d < 8; ++d) h0[d] = A[d] * invT;

        float h1[16];
        #pragma unroll
        for (int t = 0; t < 16; ++t) {
            float v = qb0[t];
            #pragma unroll
            for (int e = 0; e < 8; ++e) v += h0[e] * qw0[t * 8 + e];
            h1[t] = tanhf(v);
        }
        float h2x[16];
        #pragma unroll
        for (int t = 0; t < 16; ++t) {
            float v = qb1[t];
            #pragma unroll
            for (int e = 0; e < 16; ++e) v += h1[e] * qw1[t * 16 + e];
            h2x[t] = tanhf(v);
        }
        float h3[12];
        #pragma unroll
        for (int t = 0; t < 12; ++t) {
            float v = qb2[t];
            #pragma unroll
            for (int e = 0; e < 16; ++e) v += h2x[e] * qw2[t * 16 + e];
            h3[t] = tanhf(v);
        }
        float h4[8];
        #pragma unroll
        for (int t = 0; t < 8; ++t) {
            float v = qb3[t];
            #pragma unroll
            for (int e = 0; e < 12; ++e) v += h3[e] * qw3[t * 12 + e];
            h4[t] = tanhf(v);
        }
        float h5[4];
        #pragma unroll
        for (int t = 0; t < 4; ++t) {
            float v = qb4[t];
            #pragma unroll
            for (int e = 0; e < 8; ++e) v += h4[e] * qw4[t * 8 + e];
            h5[t] = tanhf(v);
        }
        float o = qb5[0];
        #pragma unroll
        for (int e = 0; e < 4; ++e) o += h5[e] * qw5[e];
        out[row] = 1.0f / (1.0f + expf(-o));
    }
}

extern "C" void kernel_launch(void* const* d_in, const int* in_sizes, int n_in,
                              void* d_out, int out_size, void* d_ws, size_t ws_size,
                              hipStream_t stream) {
    const float* in  = (const float*)d_in[0];
    const float* rot = (const float*)d_in[1];
    const float* ent = (const float*)d_in[2];
    const float* gw  = (const float*)d_in[3];
    const float* gb  = (const float*)d_in[4];
    const float* qw0 = (const float*)d_in[5];
    const float* qb0 = (const float*)d_in[6];
    const float* qw1 = (const float*)d_in[7];
    const float* qb1 = (const float*)d_in[8];
    const float* qw2 = (const float*)d_in[9];
    const float* qb2 = (const float*)d_in[10];
    const float* qw3 = (const float*)d_in[11];
    const float* qb3 = (const float*)d_in[12];
    const float* qw4 = (const float*)d_in[13];
    const float* qb4 = (const float*)d_in[14];
    const float* qw5 = (const float*)d_in[15];
    const float* qb5 = (const float*)d_in[16];

    // ws bytes needed = (NN*8*4 + nseg*NN*18) * 4
    auto need = [](int nseg) { return ((size_t)NN * 8 * 4 + (size_t)nseg * NN * 18) * 4; };
    const int nseg = (ws_size >= need(64)) ? 64 : 32;

    float* ws = (float*)d_ws;
    size_t off = 0;
    float* xn   = ws + off; off += (size_t)NN * 8;
    float* pns  = ws + off; off += (size_t)nseg * NN * 8;
    float* dif  = ws + off; off += (size_t)NN * 8;
    float* qsb  = ws + off; off += (size_t)NN * 8;
    float* kkb  = ws + off; off += (size_t)NN * 8;
    float* pacc = ws + off; off += (size_t)nseg * NN * 8;
    float* pm   = ws + off; off += (size_t)nseg * NN;
    float* psum = ws + off; off += (size_t)nseg * NN;

    dim3 blk(256);
    k_norm<<<dim3(NN / 256), blk, 0, stream>>>(in, xn);
    if (nseg == 64) {
        k_adj_t<64><<<dim3(NN / 2 / 256, 64), blk, 0, stream>>>(xn, in, pns);
        k_diff3<64><<<dim3(NN / 8), blk, 0, stream>>>(pns, gw, gb, rot, ent, dif, qsb, kkb);
        k_attn_t<64><<<dim3(NN / 2 / 256, 64), blk, 0, stream>>>(qsb, kkb, dif, pacc, pm, psum);
        k_merge3<64><<<dim3(NN / 8), blk, 0, stream>>>(pacc, pm, psum,
                                                       qw0, qb0, qw1, qb1, qw2, qb2,
                                                       qw3, qb3, qw4, qb4, qw5, qb5,
                                                       (float*)d_out);
    } else {
        k_adj_t<32><<<dim3(NN / 2 / 256, 32), blk, 0, stream>>>(xn, in, pns);
        k_diff3<32><<<dim3(NN / 8), blk, 0, stream>>>(pns, gw, gb, rot, ent, dif, qsb, kkb);
        k_attn_t<32><<<dim3(NN / 2 / 256, 32), blk, 0, stream>>>(qsb, kkb, dif, pacc, pm, psum);
        k_merge3<32><<<dim3(NN / 8), blk, 0, stream>>>(pacc, pm, psum,
                                                       qw0, qb0, qw1, qb1, qw2, qb2,
                                                       qw3, qb3, qw4, qb4, qw5, qb5,
                                                       (float*)d_out);
    }
}